// Round 4
// baseline (802.914 us; speedup 1.0000x reference)
//
#include <hip/hip_runtime.h>

typedef __bf16 bf16x8 __attribute__((ext_vector_type(8)));
typedef float f32x4 __attribute__((ext_vector_type(4)));
typedef unsigned int u32;
typedef u32 u32x4 __attribute__((ext_vector_type(4)));

static __device__ __forceinline__ f32x4 mfma16(bf16x8 a, bf16x8 b, f32x4 c) {
    return __builtin_amdgcn_mfma_f32_16x16x32_bf16(a, b, c, 0, 0, 0);
}

static __device__ __forceinline__ u32 packbf(float a, float b) {
    unsigned short lo = __builtin_bit_cast(unsigned short, (__bf16)a);
    unsigned short hi = __builtin_bit_cast(unsigned short, (__bf16)b);
    return (u32)lo | ((u32)hi << 16);
}

// ---------------- prep kernel: weight transpose/convert + bias matrix ----------------
// ws layout:
//   wqkvT : 576*192 bf16  (221184 B)   wqkvT[n][k] = w_qkv[k][n]
//   wprojT: 192*192 bf16  ( 73728 B)   wprojT[n][k] = w_proj[k][n]
//   biasM : 6*64*64 f32   ( 98304 B)   biasM[h][i][j]; j>=49 -> -1e30 (mask folded in)
#define OFF_WPROJT (576 * 192 * 2)
#define OFF_BIASM (576 * 192 * 2 + 192 * 192 * 2)

__global__ __launch_bounds__(256) void wsa_prep(
    const float* __restrict__ w_qkv, const float* __restrict__ w_proj,
    const float* __restrict__ bias_table,
    __bf16* __restrict__ wqkvT, __bf16* __restrict__ wprojT,
    float* __restrict__ biasM)
{
    int tid = blockIdx.x * 256 + threadIdx.x;
    const int N1 = 576 * 192;
    const int N2 = 192 * 192;
    if (tid < N1) {
        int n = tid / 192, k = tid - n * 192;
        wqkvT[tid] = (__bf16)w_qkv[k * 576 + n];
    } else if (tid < N1 + N2) {
        int i = tid - N1;
        int n = i / 192, k = i - n * 192;
        wprojT[i] = (__bf16)w_proj[k * 192 + n];
    } else if (tid < N1 + N2 + 6 * 64 * 64) {
        int i = tid - N1 - N2;
        int h = i >> 12, ij = i & 4095, r = ij >> 6, c = ij & 63;
        float v;
        if (c >= 49) v = -1e30f;                 // key mask folded into bias
        else if (r < 49) {
            int rpi = (r / 7 - c / 7 + 6) * 13 + (r % 7 - c % 7 + 6);
            v = bias_table[rpi * 6 + h];
        } else v = 0.0f;                         // garbage q-rows: finite
        biasM[i] = v;
    }
}

// ---------------- fused main kernel: 1 window/block, 3 blocks/CU ----------------
// LDS: x_lds 64x200 (25600B) + q_s/k_s/vt_s 64x72 each (3x9216B) = 53248 B
#define XS 200
#define GS 72

__global__ __launch_bounds__(256, 3) void wsa_main(
    const float* __restrict__ x, const float* __restrict__ bqkv,
    const __bf16* __restrict__ wqkvT, const __bf16* __restrict__ wprojT,
    const float* __restrict__ biasM, float* __restrict__ out)
{
    __shared__ __bf16 x_lds[64 * XS];
    __shared__ __bf16 q_s[64 * GS];
    __shared__ __bf16 k_s[64 * GS];
    __shared__ __bf16 vt_s[64 * GS];   // vt[local_dim 0..63][token]

    const int win = blockIdx.x;
    const int tid = (int)threadIdx.x;
    const int wave = tid >> 6;
    const int lane = tid & 63;
    const int g = lane >> 4;   // 0..3
    const int c = lane & 15;   // 0..15
    const float scale = 0.17677669529663687f;  // 32^-0.5

    // ---- P0: stage x -> LDS as bf16, rows >= 49 zeroed ----
    {
        const float* xw = x + (long)win * 49 * 192;
#pragma unroll
        for (int j = 0; j < 12; ++j) {
            int f = j * 1024 + tid * 4;           // flat over 64x192
            int row = f / 192, col = f - row * 192;
            u32 lo = 0, hi = 0;
            if (row < 49) {
                f32x4 v = *(const f32x4*)(xw + (long)row * 192 + col);
                lo = packbf(v[0], v[1]);
                hi = packbf(v[2], v[3]);
            }
            u32* dst = (u32*)&x_lds[row * XS + col];
            dst[0] = lo; dst[1] = hi;
        }
    }
    __syncthreads();

    const int srcA = (2 * (g & 1)) * 16 + c;
    const int srcB = srcA + 16;
    const int ghi = g >> 1;
    const int qrow = wave * 16 + c;   // this wave's query row for lane

    f32x4 p3acc[12];
#pragma unroll
    for (int i = 0; i < 12; ++i) { f32x4 z = {0.f, 0.f, 0.f, 0.f}; p3acc[i] = z; }

    for (int grp = 0; grp < 3; ++grp) {
        // ---- P1: qkv columns for this head-pair (q 64 | k 64 | v 64 cols) ----
#pragma unroll
        for (int t = 0; t < 3; ++t) {
            int tile = wave * 3 + t;        // 0..11
            int reg = tile >> 2;            // 0=q,1=k,2=v
            int lt = tile & 3;
            int lc = lt * 16 + c;           // 0..63 local col
            int gcol = reg * 192 + grp * 64 + lc;
            float bv = bqkv[gcol];
            f32x4 acc[4];
#pragma unroll
            for (int mt = 0; mt < 4; ++mt) { f32x4 z = {0.f, 0.f, 0.f, 0.f}; acc[mt] = z; }
#pragma unroll
            for (int kk = 0; kk < 6; ++kk) {
                bf16x8 b = *(const bf16x8*)(wqkvT + (long)gcol * 192 + kk * 32 + g * 8);
#pragma unroll
                for (int mt = 0; mt < 4; ++mt) {
                    bf16x8 a = *(const bf16x8*)&x_lds[(mt * 16 + c) * XS + kk * 32 + g * 8];
                    acc[mt] = mfma16(a, b, acc[mt]);
                }
            }
#pragma unroll
            for (int mt = 0; mt < 4; ++mt) {
#pragma unroll
                for (int rr = 0; rr < 4; ++rr) {
                    int row = mt * 16 + g * 4 + rr;
                    float v = acc[mt][rr] + bv;
                    if (reg == 0)      q_s[row * GS + lc] = (__bf16)(v * scale);
                    else if (reg == 1) k_s[row * GS + lc] = (__bf16)v;
                    else               vt_s[lc * GS + row] = (__bf16)v;
                }
            }
        }
        __syncthreads();

        // ---- P2: attention for heads grp*2, grp*2+1 (all swapped/transposed) ----
        bf16x8 aoB[2];
#pragma unroll
        for (int hl = 0; hl < 2; ++hl) {
            int h = grp * 2 + hl;
            bf16x8 bq = *(const bf16x8*)&q_s[qrow * GS + hl * 32 + g * 8];
            f32x4 st[4];
#pragma unroll
            for (int nt = 0; nt < 4; ++nt) {
                bf16x8 ak = *(const bf16x8*)&k_s[(nt * 16 + c) * GS + hl * 32 + g * 8];
                f32x4 z = {0.f, 0.f, 0.f, 0.f};
                st[nt] = mfma16(ak, bq, z);   // st[nt][r] = S[qrow][ktok=nt*16+4g+r]
            }
            float p[4][4];
            const float* bh = biasM + h * 4096 + qrow * 64;
#pragma unroll
            for (int nt = 0; nt < 4; ++nt) {
                f32x4 bb = *(const f32x4*)(bh + nt * 16 + 4 * g);
#pragma unroll
                for (int r = 0; r < 4; ++r) p[nt][r] = st[nt][r] + bb[r];
            }
            // softmax over ktok (16 local + 4-lane group via xor 16,32)
            float m = p[0][0];
#pragma unroll
            for (int nt = 0; nt < 4; ++nt)
#pragma unroll
                for (int r = 0; r < 4; ++r) m = fmaxf(m, p[nt][r]);
            m = fmaxf(m, __shfl_xor(m, 16));
            m = fmaxf(m, __shfl_xor(m, 32));
            float sum = 0.f;
#pragma unroll
            for (int nt = 0; nt < 4; ++nt)
#pragma unroll
                for (int r = 0; r < 4; ++r) {
                    float e = __expf(p[nt][r] - m);
                    p[nt][r] = e;
                    sum += e;
                }
            sum += __shfl_xor(sum, 16);
            sum += __shfl_xor(sum, 32);
            float pinv = 1.0f / sum;
            // pack P rows to bf16 words
            u32 w[4][2];
#pragma unroll
            for (int nt = 0; nt < 4; ++nt)
#pragma unroll
                for (int rp = 0; rp < 2; ++rp)
                    w[nt][rp] = packbf(p[nt][2 * rp] * pinv, p[nt][2 * rp + 1] * pinv);
            // redistribute -> PV B-fragment: pa[ks] halfword j = P[qrow][k=ks*32+g*8+j]
            u32 paw[2][4];
#pragma unroll
            for (int ks = 0; ks < 2; ++ks)
#pragma unroll
                for (int jw = 0; jw < 4; ++jw) {
                    int jh = jw >> 1, rp = jw & 1;
                    int src = jh ? srcB : srcA;
                    u32 R1 = (u32)__shfl((int)w[2 * ks][rp], src);
                    u32 R2 = (u32)__shfl((int)w[2 * ks + 1][rp], src);
                    paw[ks][jw] = ghi ? R2 : R1;
                }
            bf16x8 pa0, pa1;
            {
                u32x4 t0 = {paw[0][0], paw[0][1], paw[0][2], paw[0][3]};
                u32x4 t1 = {paw[1][0], paw[1][1], paw[1][2], paw[1][3]};
                pa0 = __builtin_bit_cast(bf16x8, t0);
                pa1 = __builtin_bit_cast(bf16x8, t1);
            }
            // PV^T: O^T = V^T . P^T  (A = vt rows, B = pa)
            f32x4 o0, o1;
            { f32x4 z = {0.f, 0.f, 0.f, 0.f}; o0 = z; o1 = z; }
            {
                bf16x8 a00 = *(const bf16x8*)&vt_s[(hl * 32 + c) * GS + 0 + g * 8];
                bf16x8 a01 = *(const bf16x8*)&vt_s[(hl * 32 + c) * GS + 32 + g * 8];
                o0 = mfma16(a00, pa0, o0);
                o0 = mfma16(a01, pa1, o0);
            }
            {
                bf16x8 a10 = *(const bf16x8*)&vt_s[(hl * 32 + 16 + c) * GS + 0 + g * 8];
                bf16x8 a11 = *(const bf16x8*)&vt_s[(hl * 32 + 16 + c) * GS + 32 + g * 8];
                o1 = mfma16(a10, pa0, o1);
                o1 = mfma16(a11, pa1, o1);
            }
            // o0[r] = O[qrow][h*32 + 4g + r], o1[r] = O[qrow][h*32 + 16 + 4g + r]
            // redistribute -> phase-3 B-fragment: ao[qrow][Cdim = h*32 + g*8 + j]
            u32 u0 = packbf(o0[0], o0[1]), u1 = packbf(o0[2], o0[3]);
            u32 u2 = packbf(o1[0], o1[1]), u3 = packbf(o1[2], o1[3]);
            u32 bw0, bw1, bw2, bw3;
            {
                u32 A0 = (u32)__shfl((int)u0, srcA), A2 = (u32)__shfl((int)u2, srcA);
                bw0 = ghi ? A2 : A0;
                u32 A1 = (u32)__shfl((int)u1, srcA), A3 = (u32)__shfl((int)u3, srcA);
                bw1 = ghi ? A3 : A1;
                u32 B0 = (u32)__shfl((int)u0, srcB), B2 = (u32)__shfl((int)u2, srcB);
                bw2 = ghi ? B2 : B0;
                u32 B1 = (u32)__shfl((int)u1, srcB), B3 = (u32)__shfl((int)u3, srcB);
                bw3 = ghi ? B3 : B1;
            }
            u32x4 tt = {bw0, bw1, bw2, bw3};
            aoB[hl] = __builtin_bit_cast(bf16x8, tt);
        }

        // ---- P3-partial: out^T += WprojT-chunk . aoB (K = this group's 64 dims) ----
#pragma unroll
        for (int mt2 = 0; mt2 < 12; ++mt2) {
            const __bf16* wp = wprojT + (long)(mt2 * 16 + c) * 192 + grp * 64 + g * 8;
            bf16x8 w0 = *(const bf16x8*)(wp);
            bf16x8 w1 = *(const bf16x8*)(wp + 32);
            p3acc[mt2] = mfma16(w0, aoB[0], p3acc[mt2]);
            p3acc[mt2] = mfma16(w1, aoB[1], p3acc[mt2]);
        }
        __syncthreads();
    }

    // ---- store out^T fragments: lane holds out[qrow][mt2*16+4g .. +3] ----
    if (qrow < 49) {
        float* op = out + ((long)win * 49 + qrow) * 192 + 4 * g;
#pragma unroll
        for (int mt2 = 0; mt2 < 12; ++mt2)
            *(f32x4*)(op + mt2 * 16) = p3acc[mt2];
    }
}

extern "C" void kernel_launch(void* const* d_in, const int* in_sizes, int n_in,
                              void* d_out, int out_size, void* d_ws, size_t ws_size,
                              hipStream_t stream)
{
    const float* x = (const float*)d_in[0];
    const float* w_qkv = (const float*)d_in[1];
    const float* b_qkv = (const float*)d_in[2];
    const float* bias_table = (const float*)d_in[3];
    const float* w_proj = (const float*)d_in[4];
    float* out = (float*)d_out;

    char* ws = (char*)d_ws;
    __bf16* wqkvT = (__bf16*)ws;
    __bf16* wprojT = (__bf16*)(ws + OFF_WPROJT);
    float* biasM = (float*)(ws + OFF_BIASM);

    wsa_prep<<<672, 256, 0, stream>>>(w_qkv, w_proj, bias_table, wqkvT, wprojT, biasM);
    wsa_main<<<4096, 256, 0, stream>>>(x, b_qkv, wqkvT, wprojT, biasM, out);
}

// Round 5
// 523.508 us; speedup vs baseline: 1.5337x; 1.5337x over previous
//
#include <hip/hip_runtime.h>

typedef __bf16 bf16x8 __attribute__((ext_vector_type(8)));
typedef float f32x4 __attribute__((ext_vector_type(4)));
typedef unsigned int u32;
typedef u32 u32x4 __attribute__((ext_vector_type(4)));

static __device__ __forceinline__ f32x4 mfma16(bf16x8 a, bf16x8 b, f32x4 c) {
    return __builtin_amdgcn_mfma_f32_16x16x32_bf16(a, b, c, 0, 0, 0);
}

static __device__ __forceinline__ u32 packbf(float a, float b) {
    unsigned short lo = __builtin_bit_cast(unsigned short, (__bf16)a);
    unsigned short hi = __builtin_bit_cast(unsigned short, (__bf16)b);
    return (u32)lo | ((u32)hi << 16);
}

// ---------------- prep kernel: weight transpose/convert + bias matrix ----------------
// ws layout:
//   wqkvT : 576*192 bf16  wqkvT[n][k] = w_qkv[k][n]
//   wprojT: 192*192 bf16  wprojT[n][k] = w_proj[k][n]
//   biasM : 6*64*64 f32   biasM[h][i][j]; j>=49 -> -1e30 (mask folded in)
#define OFF_WPROJT (576 * 192 * 2)
#define OFF_BIASM (576 * 192 * 2 + 192 * 192 * 2)

__global__ __launch_bounds__(256) void wsa_prep(
    const float* __restrict__ w_qkv, const float* __restrict__ w_proj,
    const float* __restrict__ bias_table,
    __bf16* __restrict__ wqkvT, __bf16* __restrict__ wprojT,
    float* __restrict__ biasM)
{
    int tid = blockIdx.x * 256 + threadIdx.x;
    const int N1 = 576 * 192;
    const int N2 = 192 * 192;
    if (tid < N1) {
        int n = tid / 192, k = tid - n * 192;
        wqkvT[tid] = (__bf16)w_qkv[k * 576 + n];
    } else if (tid < N1 + N2) {
        int i = tid - N1;
        int n = i / 192, k = i - n * 192;
        wprojT[i] = (__bf16)w_proj[k * 192 + n];
    } else if (tid < N1 + N2 + 6 * 64 * 64) {
        int i = tid - N1 - N2;
        int h = i >> 12, ij = i & 4095, r = ij >> 6, c = ij & 63;
        float v;
        if (c >= 49) v = -1e30f;                 // key mask folded into bias
        else if (r < 49) {
            int rpi = (r / 7 - c / 7 + 6) * 13 + (r % 7 - c % 7 + 6);
            v = bias_table[rpi * 6 + h];
        } else v = 0.0f;                         // garbage q-rows: finite
        biasM[i] = v;
    }
}

// ---------------- fused main kernel: 1 window/block, 3 blocks/CU ----------------
// LDS: x_lds 64x200 bf16 (25600B, later reused as ao) + q_s/k_s/vt_s 64x72 (3x9216B) = 53248 B
#define XS 200
#define GS 72

__global__ __launch_bounds__(256, 3) void wsa_main(
    const float* __restrict__ x, const float* __restrict__ bqkv,
    const __bf16* __restrict__ wqkvT, const __bf16* __restrict__ wprojT,
    const float* __restrict__ biasM, float* __restrict__ out)
{
    __shared__ __bf16 x_lds[64 * XS];  // x (bf16), later ao
    __shared__ __bf16 q_s[64 * GS];
    __shared__ __bf16 k_s[64 * GS];
    __shared__ __bf16 vt_s[64 * GS];   // vt[local_dim 0..63][token]

    const int win = blockIdx.x;
    const int tid = (int)threadIdx.x;
    const int wave = tid >> 6;
    const int lane = tid & 63;
    const int g = lane >> 4;   // 0..3
    const int c = lane & 15;   // 0..15
    const float scale = 0.17677669529663687f;  // 32^-0.5

    // ---- P0: stage x -> LDS as bf16, rows >= 49 zeroed ----
    {
        const float* xw = x + (long)win * 49 * 192;
#pragma unroll
        for (int j = 0; j < 12; ++j) {
            int f = j * 1024 + tid * 4;           // flat over 64x192
            int row = f / 192, col = f - row * 192;
            u32 lo = 0, hi = 0;
            if (row < 49) {
                f32x4 v = *(const f32x4*)(xw + (long)row * 192 + col);
                lo = packbf(v[0], v[1]);
                hi = packbf(v[2], v[3]);
            }
            u32* dst = (u32*)&x_lds[row * XS + col];
            dst[0] = lo; dst[1] = hi;
        }
    }
    __syncthreads();

    const int srcA = (2 * (g & 1)) * 16 + c;
    const int srcB = srcA + 16;
    const int ghi = g >> 1;
    const int qrow = wave * 16 + c;   // this wave's query row for lane

    u32 ostash[24];                   // raw O fragments, statically indexed

#pragma unroll
    for (int grp = 0; grp < 3; ++grp) {
        // ---- P1: qkv columns for this head-pair (q 64 | k 64 | v 64 cols) ----
#pragma unroll
        for (int t = 0; t < 3; ++t) {
            int tile = wave * 3 + t;        // 0..11
            int reg = tile >> 2;            // 0=q,1=k,2=v
            int lt = tile & 3;
            int lc = lt * 16 + c;           // 0..63 local col
            int gcol = reg * 192 + grp * 64 + lc;
            float bv = bqkv[gcol];
            f32x4 acc[4];
#pragma unroll
            for (int mt = 0; mt < 4; ++mt) { f32x4 z = {0.f, 0.f, 0.f, 0.f}; acc[mt] = z; }
#pragma unroll
            for (int kk = 0; kk < 6; ++kk) {
                bf16x8 b = *(const bf16x8*)(wqkvT + (long)gcol * 192 + kk * 32 + g * 8);
#pragma unroll
                for (int mt = 0; mt < 4; ++mt) {
                    bf16x8 a = *(const bf16x8*)&x_lds[(mt * 16 + c) * XS + kk * 32 + g * 8];
                    acc[mt] = mfma16(a, b, acc[mt]);
                }
            }
#pragma unroll
            for (int mt = 0; mt < 4; ++mt) {
#pragma unroll
                for (int rr = 0; rr < 4; ++rr) {
                    int row = mt * 16 + g * 4 + rr;
                    float v = acc[mt][rr] + bv;
                    if (reg == 0)      q_s[row * GS + lc] = (__bf16)(v * scale);
                    else if (reg == 1) k_s[row * GS + lc] = (__bf16)v;
                    else               vt_s[lc * GS + row] = (__bf16)v;
                }
            }
        }
        __syncthreads();

        // ---- P2: attention for heads grp*2, grp*2+1 (swapped QK^T; PV^T) ----
#pragma unroll
        for (int hl = 0; hl < 2; ++hl) {
            int h = grp * 2 + hl;
            bf16x8 bq = *(const bf16x8*)&q_s[qrow * GS + hl * 32 + g * 8];
            f32x4 st[4];
#pragma unroll
            for (int nt = 0; nt < 4; ++nt) {
                bf16x8 ak = *(const bf16x8*)&k_s[(nt * 16 + c) * GS + hl * 32 + g * 8];
                f32x4 z = {0.f, 0.f, 0.f, 0.f};
                st[nt] = mfma16(ak, bq, z);   // st[nt][r] = S[qrow][ktok=nt*16+4g+r]
            }
            float p[4][4];
            const float* bh = biasM + h * 4096 + qrow * 64;
#pragma unroll
            for (int nt = 0; nt < 4; ++nt) {
                f32x4 bb = *(const f32x4*)(bh + nt * 16 + 4 * g);
#pragma unroll
                for (int r = 0; r < 4; ++r) p[nt][r] = st[nt][r] + bb[r];
            }
            // softmax over ktok (16 local + 4-lane group via xor 16,32)
            float m = p[0][0];
#pragma unroll
            for (int nt = 0; nt < 4; ++nt)
#pragma unroll
                for (int r = 0; r < 4; ++r) m = fmaxf(m, p[nt][r]);
            m = fmaxf(m, __shfl_xor(m, 16));
            m = fmaxf(m, __shfl_xor(m, 32));
            float sum = 0.f;
#pragma unroll
            for (int nt = 0; nt < 4; ++nt)
#pragma unroll
                for (int r = 0; r < 4; ++r) {
                    float e = __expf(p[nt][r] - m);
                    p[nt][r] = e;
                    sum += e;
                }
            sum += __shfl_xor(sum, 16);
            sum += __shfl_xor(sum, 32);
            float pinv = 1.0f / sum;
            // pack P rows to bf16 words
            u32 w[4][2];
#pragma unroll
            for (int nt = 0; nt < 4; ++nt)
#pragma unroll
                for (int rp = 0; rp < 2; ++rp)
                    w[nt][rp] = packbf(p[nt][2 * rp] * pinv, p[nt][2 * rp + 1] * pinv);
            // redistribute -> PV B-fragment: pa[ks] halfword j = P[qrow][k=ks*32+g*8+j]
            u32 paw[2][4];
#pragma unroll
            for (int ks = 0; ks < 2; ++ks)
#pragma unroll
                for (int jw = 0; jw < 4; ++jw) {
                    int jh = jw >> 1, rp = jw & 1;
                    int src = jh ? srcB : srcA;
                    u32 R1 = (u32)__shfl((int)w[2 * ks][rp], src);
                    u32 R2 = (u32)__shfl((int)w[2 * ks + 1][rp], src);
                    paw[ks][jw] = ghi ? R2 : R1;
                }
            bf16x8 pa0, pa1;
            {
                u32x4 t0 = {paw[0][0], paw[0][1], paw[0][2], paw[0][3]};
                u32x4 t1 = {paw[1][0], paw[1][1], paw[1][2], paw[1][3]};
                pa0 = __builtin_bit_cast(bf16x8, t0);
                pa1 = __builtin_bit_cast(bf16x8, t1);
            }
            // PV^T: O^T = V^T . P^T  (A = vt rows, B = pa)
            f32x4 o0, o1;
            { f32x4 z = {0.f, 0.f, 0.f, 0.f}; o0 = z; o1 = z; }
            {
                bf16x8 a00 = *(const bf16x8*)&vt_s[(hl * 32 + c) * GS + 0 + g * 8];
                bf16x8 a01 = *(const bf16x8*)&vt_s[(hl * 32 + c) * GS + 32 + g * 8];
                o0 = mfma16(a00, pa0, o0);
                o0 = mfma16(a01, pa1, o0);
            }
            {
                bf16x8 a10 = *(const bf16x8*)&vt_s[(hl * 32 + 16 + c) * GS + 0 + g * 8];
                bf16x8 a11 = *(const bf16x8*)&vt_s[(hl * 32 + 16 + c) * GS + 32 + g * 8];
                o1 = mfma16(a10, pa0, o1);
                o1 = mfma16(a11, pa1, o1);
            }
            // o0[r] = O[qrow][h*32 + 4g + r], o1[r] = O[qrow][h*32 + 16 + 4g + r]
            // stash packed (cols 4g..4g+3 are register-consecutive -> two u32 each)
            ostash[grp * 8 + hl * 4 + 0] = packbf(o0[0], o0[1]);
            ostash[grp * 8 + hl * 4 + 1] = packbf(o0[2], o0[3]);
            ostash[grp * 8 + hl * 4 + 2] = packbf(o1[0], o1[1]);
            ostash[grp * 8 + hl * 4 + 3] = packbf(o1[2], o1[3]);
        }
        __syncthreads();   // q_s/k_s/vt_s reused next grp; also last x_lds read done
    }

    // ---- write stashed O into x_lds (x dead) as ao[row][col], row-major ----
#pragma unroll
    for (int grp = 0; grp < 3; ++grp)
#pragma unroll
        for (int hl = 0; hl < 2; ++hl) {
            int h = grp * 2 + hl;
            u32* d0 = (u32*)&x_lds[qrow * XS + h * 32 + 4 * g];
            d0[0] = ostash[grp * 8 + hl * 4 + 0];
            d0[1] = ostash[grp * 8 + hl * 4 + 1];
            u32* d1 = (u32*)&x_lds[qrow * XS + h * 32 + 16 + 4 * g];
            d1[0] = ostash[grp * 8 + hl * 4 + 2];
            d1[1] = ostash[grp * 8 + hl * 4 + 3];
        }
    __syncthreads();

    // ---- P3: out = ao @ Wproj (M=64, K=192, N=192), coalesced row-major stores ----
    for (int t = 0; t < 3; ++t) {
        int nt = wave * 3 + t;
        int col = nt * 16 + c;  // 0..191
        f32x4 acc[4];
#pragma unroll
        for (int m2 = 0; m2 < 4; ++m2) { f32x4 z = {0.f, 0.f, 0.f, 0.f}; acc[m2] = z; }
#pragma unroll
        for (int kk = 0; kk < 6; ++kk) {
            bf16x8 b = *(const bf16x8*)(wprojT + (long)col * 192 + kk * 32 + g * 8);
#pragma unroll
            for (int m2 = 0; m2 < 4; ++m2) {
                bf16x8 a = *(const bf16x8*)&x_lds[(m2 * 16 + c) * XS + kk * 32 + g * 8];
                acc[m2] = mfma16(a, b, acc[m2]);
            }
        }
#pragma unroll
        for (int m2 = 0; m2 < 4; ++m2) {
#pragma unroll
            for (int r = 0; r < 4; ++r) {
                int row = m2 * 16 + g * 4 + r;
                if (row < 49)
                    out[((long)win * 49 + row) * 192 + col] = acc[m2][r];
            }
        }
    }
}

extern "C" void kernel_launch(void* const* d_in, const int* in_sizes, int n_in,
                              void* d_out, int out_size, void* d_ws, size_t ws_size,
                              hipStream_t stream)
{
    const float* x = (const float*)d_in[0];
    const float* w_qkv = (const float*)d_in[1];
    const float* b_qkv = (const float*)d_in[2];
    const float* bias_table = (const float*)d_in[3];
    const float* w_proj = (const float*)d_in[4];
    float* out = (float*)d_out;

    char* ws = (char*)d_ws;
    __bf16* wqkvT = (__bf16*)ws;
    __bf16* wprojT = (__bf16*)(ws + OFF_WPROJT);
    float* biasM = (float*)(ws + OFF_BIASM);

    wsa_prep<<<672, 256, 0, stream>>>(w_qkv, w_proj, bias_table, wqkvT, wprojT, biasM);
    wsa_main<<<4096, 256, 0, stream>>>(x, b_qkv, wqkvT, wprojT, biasM, out);
}